// Round 3
// baseline (142.321 us; speedup 1.0000x reference)
//
#include <hip/hip_runtime.h>

// MergeLayer: out = sigmoid(relu([z[e0]; z[e1]] @ W1 + b1) @ W2 + b2)
// Factored: g = z @ Wcat (+b1 on gi half)  -- node-level GEMM via bf16 MFMA
//           out[k] = sigmoid(dot(relu(gi[e0]+gj[e1]), W2) + b2)  -- edge gather
// ws layout: gi (N*128 bf16) | gj (N*128 bf16) | Wt (256x128 bf16, 64KB)
//
// MFMA operand order: A = Wt rows (m=channel), B = z (n=node). C/D layout
// (col=lane&15 -> node, row=quad*4+reg -> channel) then gives each lane 4
// CONSECUTIVE channels of one node -> vectorized ushort4 epilogue stores
// (32 x 8B per lane instead of 128 x 2B scalar).

#define DD 128

typedef __attribute__((ext_vector_type(8))) short short8;
typedef __attribute__((ext_vector_type(4))) float floatx4;

static __device__ __forceinline__ unsigned short f2bf(float f) {
  unsigned int u = __builtin_bit_cast(unsigned int, f);
  u += 0x7fffu + ((u >> 16) & 1u);   // round-to-nearest-even
  return (unsigned short)(u >> 16);
}
static __device__ __forceinline__ float bflo(unsigned int u) {
  return __builtin_bit_cast(float, u << 16);
}
static __device__ __forceinline__ float bfhi(unsigned int u) {
  return __builtin_bit_cast(float, u & 0xffff0000u);
}

// ---------- prelude: Wt[c][k] = Wcat[k][c] as bf16 ---------------------------
// Wcat[k][c] = (c<128) ? W1[k][c] : W1[128+k][c-128];  W1 is [256][128] fp32.
__global__ __launch_bounds__(256) void wt_build(
    const float* __restrict__ W1, unsigned short* __restrict__ Wt) {
  const int g = blockIdx.x * 256 + threadIdx.x;  // 8192 threads total
  const int c = g >> 5;                          // 0..255
  const int kq = (g & 31) * 4;                   // 0..124
  const float* src = (c < 128) ? (W1 + c) : (W1 + 128 * 128 + (c - 128));
  ushort4 o;
  o.x = f2bf(src[(size_t)(kq + 0) * 128]);
  o.y = f2bf(src[(size_t)(kq + 1) * 128]);
  o.z = f2bf(src[(size_t)(kq + 2) * 128]);
  o.w = f2bf(src[(size_t)(kq + 3) * 128]);
  *(ushort4*)&Wt[c * 128 + kq] = o;
}

// ---------- node GEMM via mfma_f32_16x16x32_bf16 (A=W, B=z) ------------------
// Block: 256 threads = 4 waves, 128 nodes. Wave w: nodes [nb+32w, nb+32w+32).
// Per wave: 16 M-tiles (channels) x 2 N-tiles (nodes) x 4 k-steps = 128 MFMA.
__global__ __launch_bounds__(256) void node_mfma(
    const float* __restrict__ z, const unsigned short* __restrict__ Wt,
    const float* __restrict__ b1, unsigned short* __restrict__ gi,
    unsigned short* __restrict__ gj, int n_nodes) {
  __shared__ unsigned short zb[128 * 136];  // 34.8 KB; row stride 136
  const int tid = threadIdx.x;
  const int nb = blockIdx.x * 128;

  // stage z tile -> bf16 LDS (coalesced float4 reads)
#pragma unroll
  for (int i = 0; i < 16; ++i) {
    int q = tid + i * 256;            // 4096 float4 = 128 nodes x 32
    int nl = q >> 5;
    int node = nb + nl; if (node >= n_nodes) node = n_nodes - 1;
    float4 v = ((const float4*)z)[(size_t)node * 32 + (q & 31)];
    ushort4 o;
    o.x = f2bf(v.x); o.y = f2bf(v.y); o.z = f2bf(v.z); o.w = f2bf(v.w);
    *(ushort4*)&zb[nl * 136 + (q & 31) * 4] = o;
  }
  __syncthreads();

  const int w = tid >> 6, lane = tid & 63;
  const int l15 = lane & 15, quad = lane >> 4;

  // B fragments (z): B[k=quad*8+j][n=lane&15], n -> node (m89/m120 layouts)
  short8 bz[2][4];
#pragma unroll
  for (int nt = 0; nt < 2; ++nt)
#pragma unroll
    for (int s = 0; s < 4; ++s)
      bz[nt][s] = *(const short8*)&zb[(w * 32 + nt * 16 + l15) * 136 + s * 32 + quad * 8];

  floatx4 acc[2][16];
#pragma unroll
  for (int t = 0; t < 16; ++t) {
    floatx4 bias = {0.f, 0.f, 0.f, 0.f};
    if (t < 8) {  // b1 folded into gi half; row = channel = t*16 + quad*4 + r
      float4 b4 = *(const float4*)&b1[t * 16 + quad * 4];
      bias[0] = b4.x; bias[1] = b4.y; bias[2] = b4.z; bias[3] = b4.w;
    }
    acc[0][t] = bias; acc[1][t] = bias;
  }

  // A fragments (W) straight from global Wt (64KB, L1/L2-hot)
#pragma unroll
  for (int t = 0; t < 16; ++t) {
    const unsigned short* wrow = Wt + (size_t)(t * 16 + l15) * 128 + quad * 8;
#pragma unroll
    for (int s = 0; s < 4; ++s) {
      short8 a = *(const short8*)(wrow + s * 32);
      acc[0][t] = __builtin_amdgcn_mfma_f32_16x16x32_bf16(a, bz[0][s], acc[0][t], 0, 0, 0);
      acc[1][t] = __builtin_amdgcn_mfma_f32_16x16x32_bf16(a, bz[1][s], acc[1][t], 0, 0, 0);
    }
  }

  // epilogue: col=lane&15 -> node, row=quad*4+r -> channel. 4 consecutive
  // channels per lane -> ushort4 (8B) stores, 32 per lane.
#pragma unroll
  for (int nt = 0; nt < 2; ++nt) {
    const int node = nb + w * 32 + nt * 16 + l15;
    if (node < n_nodes) {
#pragma unroll
      for (int t = 0; t < 16; ++t) {
        unsigned short* base = (t < 8) ? gi : gj;
        const int c = t * 16 + quad * 4 - ((t < 8) ? 0 : 128);
        ushort4 o;
        o.x = f2bf(acc[nt][t][0]); o.y = f2bf(acc[nt][t][1]);
        o.z = f2bf(acc[nt][t][2]); o.w = f2bf(acc[nt][t][3]);
        *(ushort4*)&base[(size_t)node * 128 + c] = o;
      }
    }
  }
}

// ---------- edge phase: 8 lanes per edge, 2 edges per lane-group --------------
static __device__ __forceinline__ float dot8(uint4 a, uint4 b, float4 w0, float4 w1) {
  float s;
  s = fmaxf(bflo(a.x) + bflo(b.x), 0.f) * w0.x;
  s = fmaf(fmaxf(bfhi(a.x) + bfhi(b.x), 0.f), w0.y, s);
  s = fmaf(fmaxf(bflo(a.y) + bflo(b.y), 0.f), w0.z, s);
  s = fmaf(fmaxf(bfhi(a.y) + bfhi(b.y), 0.f), w0.w, s);
  s = fmaf(fmaxf(bflo(a.z) + bflo(b.z), 0.f), w1.x, s);
  s = fmaf(fmaxf(bfhi(a.z) + bfhi(b.z), 0.f), w1.y, s);
  s = fmaf(fmaxf(bflo(a.w) + bflo(b.w), 0.f), w1.z, s);
  s = fmaf(fmaxf(bfhi(a.w) + bfhi(b.w), 0.f), w1.w, s);
  return s;
}

__global__ __launch_bounds__(256) void edge_mlp(
    const int* __restrict__ e, const unsigned short* __restrict__ gi,
    const unsigned short* __restrict__ gj, const float* __restrict__ W2,
    const float* __restrict__ b2, float* __restrict__ out, int E) {
  __shared__ float w2s[128];
  if (threadIdx.x < 128) w2s[threadIdx.x] = W2[threadIdx.x];
  __syncthreads();
  const int lane = threadIdx.x & 63;
  const int gw   = (int)((blockIdx.x * 256u + threadIdx.x) >> 6);
  const int p    = lane & 7;
  const int eA   = gw * 16 + (lane >> 3) * 2;  // this group's two edges
  const int eB   = eA + 1;

  const float4* wv = (const float4*)w2s;
  const float4 w0 = wv[p * 2],      w1 = wv[p * 2 + 1];
  const float4 w2 = wv[16 + p * 2], w3 = wv[16 + p * 2 + 1];

  float accA = 0.f, accB = 0.f;
  if (eA < E) {
    const int iA = e[eA],     jA = e[E + eA];
    const int iB = e[eB],     jB = e[E + eB];   // eB<E whenever eA<E (E%16==0 pad-safe)
    // 8 lanes x 16B cover each 128B line of the 256B rows; 8 loads in flight.
    const uint4* piA = (const uint4*)(gi + (size_t)iA * 128);
    const uint4* pjA = (const uint4*)(gj + (size_t)jA * 128);
    const uint4* piB = (const uint4*)(gi + (size_t)iB * 128);
    const uint4* pjB = (const uint4*)(gj + (size_t)jB * 128);
    uint4 a0 = piA[p], a1 = piA[8 + p], c0 = pjA[p], c1 = pjA[8 + p];
    uint4 d0 = piB[p], d1 = piB[8 + p], f0 = pjB[p], f1 = pjB[8 + p];
    accA = dot8(a0, c0, w0, w1) + dot8(a1, c1, w2, w3);
    accB = dot8(d0, f0, w0, w1) + dot8(d1, f1, w2, w3);
  }
  accA += __shfl_xor(accA, 1); accB += __shfl_xor(accB, 1);
  accA += __shfl_xor(accA, 2); accB += __shfl_xor(accB, 2);
  accA += __shfl_xor(accA, 4); accB += __shfl_xor(accB, 4);
  // lane p==0 writes edge A, lane p==1 writes edge B (consecutive addresses)
  if (eA < E && p < 2) {
    float x = (p == 0 ? accA : accB) + b2[0];
    out[eA + p] = 1.f / (1.f + __expf(-x));
  }
}

// ---------- fallback (workspace too small): wave per edge ---------------------
__global__ __launch_bounds__(256) void edge_direct(
    const int* __restrict__ e, const float* __restrict__ z,
    const float* __restrict__ W1, const float* __restrict__ b1,
    const float* __restrict__ W2, const float* __restrict__ b2,
    float* __restrict__ out, int E) {
  const int lane = threadIdx.x & 63;
  const int edge = (int)((blockIdx.x * 256u + threadIdx.x) >> 6);
  if (edge >= E) return;
  const int i = e[edge], j = e[E + edge];
  const float* zi = z + (size_t)i * 128;
  const float* zj = z + (size_t)j * 128;
  const int c0 = lane * 2;
  float h0 = b1[c0], h1 = b1[c0 + 1];
  for (int k = 0; k < 128; ++k) {
    float a = zi[k], b = zj[k];
    float2 wt = *(const float2*)&W1[(size_t)k * 128 + c0];
    float2 wb = *(const float2*)&W1[(size_t)(128 + k) * 128 + c0];
    h0 = fmaf(a, wt.x, h0); h1 = fmaf(a, wt.y, h1);
    h0 = fmaf(b, wb.x, h0); h1 = fmaf(b, wb.y, h1);
  }
  float s = fmaxf(h0, 0.f) * W2[c0] + fmaxf(h1, 0.f) * W2[c0 + 1];
#pragma unroll
  for (int off = 1; off < 64; off <<= 1) s += __shfl_xor(s, off);
  if (lane == 0) out[edge] = 1.f / (1.f + __expf(-(s + b2[0])));
}

extern "C" void kernel_launch(void* const* d_in, const int* in_sizes, int n_in,
                              void* d_out, int out_size, void* d_ws, size_t ws_size,
                              hipStream_t stream) {
  const float* z  = (const float*)d_in[0];
  const int*   e  = (const int*)d_in[1];
  const float* W1 = (const float*)d_in[2];
  const float* b1 = (const float*)d_in[3];
  const float* W2 = (const float*)d_in[4];
  const float* b2 = (const float*)d_in[5];
  float* out = (float*)d_out;
  const int n_nodes = in_sizes[0] / DD;  // 50000
  const int E = in_sizes[1] / 2;         // 600000

  const size_t g_bytes = (size_t)n_nodes * DD * sizeof(unsigned short);
  const size_t wt_bytes = 256 * 128 * sizeof(unsigned short);  // 64 KB
  if (ws_size >= 2 * g_bytes + wt_bytes) {
    unsigned short* gi = (unsigned short*)d_ws;
    unsigned short* gj = (unsigned short*)((char*)d_ws + g_bytes);
    unsigned short* Wt = (unsigned short*)((char*)d_ws + 2 * g_bytes);
    wt_build<<<32, 256, 0, stream>>>(W1, Wt);
    node_mfma<<<(n_nodes + 127) / 128, 256, 0, stream>>>(z, Wt, b1, gi, gj, n_nodes);
    const int pairs16 = (E + 15) / 16;                  // edges per wave = 16
    edge_mlp<<<(pairs16 + 3) / 4, 256, 0, stream>>>(e, gi, gj, W2, b2, out, E);
  } else {
    edge_direct<<<(E + 3) / 4, 256, 0, stream>>>(e, z, W1, b1, W2, b2, out, E);
  }
}

// Round 4
// 134.287 us; speedup vs baseline: 1.0598x; 1.0598x over previous
//
#include <hip/hip_runtime.h>

// MergeLayer: out = sigmoid(relu([z[e0]; z[e1]] @ W1 + b1) @ W2 + b2)
// Factored: g = z @ Wcat (+b1 on gi half)  -- node-level GEMM via bf16 MFMA
//           out[k] = sigmoid(dot(relu(gi[e0]+gj[e1]), W2) + b2)  -- edge gather
// ws layout: gi (N*128 bf16) | gj (N*128 bf16) | Wt (256x128 bf16, 64KB)
//
// Edge kernel is PERSISTENT (grid-stride, 2048 blocks): no per-block LDS
// staging/barrier, W2 in registers, ~9 iterations per wave amortize preamble.
// Node kernel splits channels across waves (4 t-tiles each) over 64-node
// blocks: Wt is read once per block instead of 4x.

#define DD 128

typedef __attribute__((ext_vector_type(8))) short short8;
typedef __attribute__((ext_vector_type(4))) float floatx4;

static __device__ __forceinline__ unsigned short f2bf(float f) {
  unsigned int u = __builtin_bit_cast(unsigned int, f);
  u += 0x7fffu + ((u >> 16) & 1u);   // round-to-nearest-even
  return (unsigned short)(u >> 16);
}
static __device__ __forceinline__ float bflo(unsigned int u) {
  return __builtin_bit_cast(float, u << 16);
}
static __device__ __forceinline__ float bfhi(unsigned int u) {
  return __builtin_bit_cast(float, u & 0xffff0000u);
}

// ---------- prelude: Wt[c][k] = Wcat[k][c] as bf16 ---------------------------
// Wcat[k][c] = (c<128) ? W1[k][c] : W1[128+k][c-128];  W1 is [256][128] fp32.
__global__ __launch_bounds__(256) void wt_build(
    const float* __restrict__ W1, unsigned short* __restrict__ Wt) {
  const int g = blockIdx.x * 256 + threadIdx.x;  // 8192 threads total
  const int c = g >> 5;                          // 0..255
  const int kq = (g & 31) * 4;                   // 0..124
  const float* src = (c < 128) ? (W1 + c) : (W1 + 128 * 128 + (c - 128));
  ushort4 o;
  o.x = f2bf(src[(size_t)(kq + 0) * 128]);
  o.y = f2bf(src[(size_t)(kq + 1) * 128]);
  o.z = f2bf(src[(size_t)(kq + 2) * 128]);
  o.w = f2bf(src[(size_t)(kq + 3) * 128]);
  *(ushort4*)&Wt[c * 128 + kq] = o;
}

// ---------- node GEMM via mfma_f32_16x16x32_bf16 (A=W, B=z) ------------------
// Block: 256 threads = 4 waves, 64 nodes (4 node-tiles). Wave w owns channel
// tiles t = 4w..4w+3 (64 channels) for ALL 4 node-tiles.
// Per wave: 16 A-loads (16B, L1-hot Wt), 16 ds_read_b128, 64 MFMA.
__global__ __launch_bounds__(256) void node_mfma(
    const float* __restrict__ z, const unsigned short* __restrict__ Wt,
    const float* __restrict__ b1, unsigned short* __restrict__ gi,
    unsigned short* __restrict__ gj, int n_nodes) {
  __shared__ unsigned short zb[64 * 136];  // 17.4 KB; row stride 136
  const int tid = threadIdx.x;
  const int nb = blockIdx.x * 64;

  // stage z tile -> bf16 LDS (coalesced float4 reads; 8 per thread)
#pragma unroll
  for (int i = 0; i < 8; ++i) {
    int q = tid + i * 256;            // 2048 float4 = 64 nodes x 32
    int nl = q >> 5;
    int node = nb + nl; if (node >= n_nodes) node = n_nodes - 1;
    float4 v = ((const float4*)z)[(size_t)node * 32 + (q & 31)];
    ushort4 o;
    o.x = f2bf(v.x); o.y = f2bf(v.y); o.z = f2bf(v.z); o.w = f2bf(v.w);
    *(ushort4*)&zb[nl * 136 + (q & 31) * 4] = o;
  }

  const int w = tid >> 6, lane = tid & 63;
  const int l15 = lane & 15, quad = lane >> 4;

  // A fragments (W): A[m=lane&15][k=quad*8+j]; t_global = w*4+tt
  short8 a[4][4];
#pragma unroll
  for (int tt = 0; tt < 4; ++tt) {
    const unsigned short* wrow =
        Wt + (size_t)((w * 4 + tt) * 16 + l15) * 128 + quad * 8;
#pragma unroll
    for (int s = 0; s < 4; ++s) a[tt][s] = *(const short8*)(wrow + s * 32);
  }

  floatx4 acc[4][4];  // [tt][nt]
#pragma unroll
  for (int tt = 0; tt < 4; ++tt) {
    floatx4 bias = {0.f, 0.f, 0.f, 0.f};
    if (w < 2) {  // gi half: b1 folded; channel = (w*4+tt)*16 + quad*4 + r
      float4 b4 = *(const float4*)&b1[(w * 4 + tt) * 16 + quad * 4];
      bias[0] = b4.x; bias[1] = b4.y; bias[2] = b4.z; bias[3] = b4.w;
    }
#pragma unroll
    for (int nt = 0; nt < 4; ++nt) acc[tt][nt] = bias;
  }

  __syncthreads();

#pragma unroll
  for (int nt = 0; nt < 4; ++nt) {
    short8 bz[4];  // B[k=quad*8+j][n=lane&15], n -> node
#pragma unroll
    for (int s = 0; s < 4; ++s)
      bz[s] = *(const short8*)&zb[(nt * 16 + l15) * 136 + s * 32 + quad * 8];
#pragma unroll
    for (int tt = 0; tt < 4; ++tt)
#pragma unroll
      for (int s = 0; s < 4; ++s)
        acc[tt][nt] =
            __builtin_amdgcn_mfma_f32_16x16x32_bf16(a[tt][s], bz[s], acc[tt][nt], 0, 0, 0);
  }

  // epilogue: col=lane&15 -> node, row=quad*4+r -> channel (4 consecutive)
  unsigned short* base = (w < 2) ? gi : gj;
  const int cbase = w * 64 - ((w < 2) ? 0 : 128);
#pragma unroll
  for (int nt = 0; nt < 4; ++nt) {
    const int node = nb + nt * 16 + l15;
    if (node < n_nodes) {
#pragma unroll
      for (int tt = 0; tt < 4; ++tt) {
        const int c = cbase + tt * 16 + quad * 4;
        ushort4 o;
        o.x = f2bf(acc[tt][nt][0]); o.y = f2bf(acc[tt][nt][1]);
        o.z = f2bf(acc[tt][nt][2]); o.w = f2bf(acc[tt][nt][3]);
        *(ushort4*)&base[(size_t)node * 128 + c] = o;
      }
    }
  }
}

// ---------- edge phase: persistent, 8 lanes per edge, W2 in registers ---------
static __device__ __forceinline__ float dot8(uint4 a, uint4 b, float4 w0, float4 w1) {
  float s;
  s = fmaxf(bflo(a.x) + bflo(b.x), 0.f) * w0.x;
  s = fmaf(fmaxf(bfhi(a.x) + bfhi(b.x), 0.f), w0.y, s);
  s = fmaf(fmaxf(bflo(a.y) + bflo(b.y), 0.f), w0.z, s);
  s = fmaf(fmaxf(bfhi(a.y) + bfhi(b.y), 0.f), w0.w, s);
  s = fmaf(fmaxf(bflo(a.z) + bflo(b.z), 0.f), w1.x, s);
  s = fmaf(fmaxf(bfhi(a.z) + bfhi(b.z), 0.f), w1.y, s);
  s = fmaf(fmaxf(bflo(a.w) + bflo(b.w), 0.f), w1.z, s);
  s = fmaf(fmaxf(bfhi(a.w) + bfhi(b.w), 0.f), w1.w, s);
  return s;
}

__global__ __launch_bounds__(256) void edge_mlp(
    const int* __restrict__ e, const unsigned short* __restrict__ gi,
    const unsigned short* __restrict__ gj, const float* __restrict__ W2,
    const float* __restrict__ b2, float* __restrict__ out, int E) {
  const int p = threadIdx.x & 7;
  // W2 chunk for this lane, held in 16 VGPRs (512B table, L2-hot; once/wave)
  const float4* wv = (const float4*)W2;
  const float4 w0 = wv[p * 2],      w1 = wv[p * 2 + 1];
  const float4 w2 = wv[16 + p * 2], w3 = wv[16 + p * 2 + 1];
  const float bias2 = b2[0];

  const int stride = gridDim.x * 32;  // 32 edges per block per iteration
  for (int edge = blockIdx.x * 32 + (threadIdx.x >> 3); edge < E; edge += stride) {
    const int i = e[edge];
    const int j = e[E + edge];
    // 8 lanes x 16B cover each 128B line of the two 256B rows, fully used.
    const uint4* pi = (const uint4*)(gi + (size_t)i * 128);
    const uint4* pj = (const uint4*)(gj + (size_t)j * 128);
    uint4 a0 = pi[p], a1 = pi[8 + p];
    uint4 c0 = pj[p], c1 = pj[8 + p];
    float acc = dot8(a0, c0, w0, w1) + dot8(a1, c1, w2, w3);
    acc += __shfl_xor(acc, 1);
    acc += __shfl_xor(acc, 2);
    acc += __shfl_xor(acc, 4);
    if (p == 0) {
      float x = acc + bias2;
      out[edge] = 1.f / (1.f + __expf(-x));
    }
  }
}

// ---------- fallback (workspace too small): wave per edge ---------------------
__global__ __launch_bounds__(256) void edge_direct(
    const int* __restrict__ e, const float* __restrict__ z,
    const float* __restrict__ W1, const float* __restrict__ b1,
    const float* __restrict__ W2, const float* __restrict__ b2,
    float* __restrict__ out, int E) {
  const int lane = threadIdx.x & 63;
  const int edge = (int)((blockIdx.x * 256u + threadIdx.x) >> 6);
  if (edge >= E) return;
  const int i = e[edge], j = e[E + edge];
  const float* zi = z + (size_t)i * 128;
  const float* zj = z + (size_t)j * 128;
  const int c0 = lane * 2;
  float h0 = b1[c0], h1 = b1[c0 + 1];
  for (int k = 0; k < 128; ++k) {
    float a = zi[k], b = zj[k];
    float2 wt = *(const float2*)&W1[(size_t)k * 128 + c0];
    float2 wb = *(const float2*)&W1[(size_t)(128 + k) * 128 + c0];
    h0 = fmaf(a, wt.x, h0); h1 = fmaf(a, wt.y, h1);
    h0 = fmaf(b, wb.x, h0); h1 = fmaf(b, wb.y, h1);
  }
  float s = fmaxf(h0, 0.f) * W2[c0] + fmaxf(h1, 0.f) * W2[c0 + 1];
#pragma unroll
  for (int off = 1; off < 64; off <<= 1) s += __shfl_xor(s, off);
  if (lane == 0) out[edge] = 1.f / (1.f + __expf(-(s + b2[0])));
}

extern "C" void kernel_launch(void* const* d_in, const int* in_sizes, int n_in,
                              void* d_out, int out_size, void* d_ws, size_t ws_size,
                              hipStream_t stream) {
  const float* z  = (const float*)d_in[0];
  const int*   e  = (const int*)d_in[1];
  const float* W1 = (const float*)d_in[2];
  const float* b1 = (const float*)d_in[3];
  const float* W2 = (const float*)d_in[4];
  const float* b2 = (const float*)d_in[5];
  float* out = (float*)d_out;
  const int n_nodes = in_sizes[0] / DD;  // 50000
  const int E = in_sizes[1] / 2;         // 600000

  const size_t g_bytes = (size_t)n_nodes * DD * sizeof(unsigned short);
  const size_t wt_bytes = 256 * 128 * sizeof(unsigned short);  // 64 KB
  if (ws_size >= 2 * g_bytes + wt_bytes) {
    unsigned short* gi = (unsigned short*)d_ws;
    unsigned short* gj = (unsigned short*)((char*)d_ws + g_bytes);
    unsigned short* Wt = (unsigned short*)((char*)d_ws + 2 * g_bytes);
    wt_build<<<32, 256, 0, stream>>>(W1, Wt);
    node_mfma<<<(n_nodes + 63) / 64, 256, 0, stream>>>(z, Wt, b1, gi, gj, n_nodes);
    edge_mlp<<<2048, 256, 0, stream>>>(e, gi, gj, W2, b2, out, E);
  } else {
    edge_direct<<<(E + 3) / 4, 256, 0, stream>>>(e, z, W1, b1, W2, b2, out, E);
  }
}